// Round 9
// baseline (279.631 us; speedup 1.0000x reference)
//
#include <hip/hip_runtime.h>
#include <math.h>

#define NC 16
#define NBINS 15
#define NCELL (NC * NBINS)   // 240
#define GRID 2048
#define VITERS 16            // float4s per thread: 2048*256*16*4 = 33,554,432 elems
#define BROWS 2097152.0      // B (rows)
#define MAXREP 8

typedef float floatx4 __attribute__((ext_vector_type(4)));

// VALU-pipe cross-lane add within rows of 16 (row_shr, 0-fill at row edge).
template <int CTRL>
__device__ __forceinline__ unsigned int dpp_add(unsigned int v) {
    return v + (unsigned int)__builtin_amdgcn_update_dpp(0, (int)v, CTRL, 0xF, 0xF, true);
}

// Non-temporal 16B load (nt bit): logits don't allocate in L3, so targets
// (134 MB) stay L3-resident across dispatches. Proven +20% in R8.
__device__ __forceinline__ float4 ldnt(const float4* p) {
    floatx4 v = __builtin_nontemporal_load((const floatx4*)p);
    return make_float4(v.x, v.y, v.z, v.w);
}

// Process one pair of float4s (8 elements) into acc. Macro (not function) so
// acc indexing stays trivially static; internal names chosen to avoid the
// .x/.y/.z/.w macro-capture bug from R2.
#define PROCESS(LV0, LV1, TV0, TV1)                                          \
    {                                                                        \
        float4 lvv[2] = {LV0, LV1};                                          \
        float4 tvv[2] = {TV0, TV1};                                          \
        _Pragma("unroll") for (int m = 0; m < 2; ++m) {                      \
            float xs[4]  = {lvv[m].x, lvv[m].y, lvv[m].z, lvv[m].w};         \
            float tvs[4] = {tvv[m].x, tvv[m].y, tvv[m].z, tvv[m].w};         \
            int bs[4];                                                       \
            unsigned int us[4];                                              \
            _Pragma("unroll") for (int j = 0; j < 4; ++j) {                  \
                float e = __builtin_amdgcn_exp2f(-xs[j] * LOG2E);            \
                float p = __builtin_amdgcn_rcpf(1.0f + e);                   \
                bs[j] = (int)(p * 15.0f); /* p==1 -> 15 -> matches nothing */\
                us[j] = (unsigned int)(fmaf(tvs[j], 262144.0f,               \
                                            fmaf(p, 1024.0f, 0.5f))) +      \
                        (1u << 25);                                          \
            }                                                                \
            _Pragma("unroll") for (int j = 0; j < 4; ++j)                    \
                _Pragma("unroll") for (int b = 0; b < NBINS; ++b)            \
                    acc[j][b] += (bs[j] == b) ? us[j] : 0u;                  \
        }                                                                    \
    }

// R8 post-mortem: nt-logits lifted 106->85us (targets now L3-resident, FETCH
// = logits only). Remaining gap: logits stream runs at just 1.6 TB/s with
// VALU 51%, occupancy 36% -> dependent-chain load->wait->compute serialization
// (VGPR=64: compiler didn't pipeline). Fix: explicit A/B double-buffer
// prefetch, up to 8 dwordx4 in flight/wave. Scatter/fold/flush identical to
// the passing R8 kernel.
__global__ void __launch_bounds__(256, 4)
ece_partial(const float4* __restrict__ logits,
            const float4* __restrict__ targets,
            float* __restrict__ ws, int nrep) {
    __shared__ unsigned int h[64 * 60];  // 15,360 B

    const float LOG2E = 1.4426950408889634f;
    const int tid = blockIdx.x * 256 + threadIdx.x;
    const int S   = GRID * 256;  // float4 stride

    unsigned int acc[4][NBINS];
#pragma unroll
    for (int j = 0; j < 4; ++j)
#pragma unroll
        for (int b = 0; b < NBINS; ++b) acc[j][b] = 0u;

    // Prologue: buffer A <- k = 0,1
    float4 lA0 = ldnt(&logits[tid]);
    float4 lA1 = ldnt(&logits[tid + S]);
    float4 tA0 = targets[tid];
    float4 tA1 = targets[tid + S];

    for (int k = 0; k < VITERS; k += 4) {
        // Issue B (k+2, k+3) before touching A.
        int ib0 = tid + (k + 2) * S, ib1 = ib0 + S;
        float4 lB0 = ldnt(&logits[ib0]);
        float4 lB1 = ldnt(&logits[ib1]);
        float4 tB0 = targets[ib0];
        float4 tB1 = targets[ib1];

        PROCESS(lA0, lA1, tA0, tA1)

        // Issue A-next (k+4, k+5); clamp on last iter (dummy, L2-hot).
        int kn  = (k + 4 < VITERS) ? (k + 4) : 0;
        int ia0 = tid + kn * S, ia1 = ia0 + S;
        lA0 = ldnt(&logits[ia0]);
        lA1 = ldnt(&logits[ia1]);
        tA0 = targets[ia0];
        tA1 = targets[ia1];

        PROCESS(lB0, lB1, tB0, tB1)
    }

    // Fold the 4 same-class lanes of each row (lanes q,q+4,q+8,q+12 share
    // tid&3 = q): after shr4+shr8, lane 12+q of each row holds the group sum.
#pragma unroll
    for (int j = 0; j < 4; ++j)
#pragma unroll
        for (int b = 0; b < NBINS; ++b) {
            unsigned int v = acc[j][b];
            v = dpp_add<0x114>(v);  // row_shr:4
            v = dpp_add<0x118>(v);  // row_shr:8
            acc[j][b] = v;
        }

    const int lane = threadIdx.x & 63;
    const int w    = threadIdx.x >> 6;
    const int r    = lane >> 4;
    const int q    = lane & 3;
    if ((lane & 15) >= 12) {  // writer lanes: 12+q of each row, q = lane&3
        unsigned int* dst = &h[((w * 4 + r) * 4 + q) * 60];
#pragma unroll
        for (int j = 0; j < 4; ++j)
#pragma unroll
            for (int b = 0; b < NBINS; ++b) dst[j * NBINS + b] = acc[j][b];
    }
    __syncthreads();

    // 240 reducers: cell (bin bb, class c = 4q+j) = sum of 16 partials
    // (4 waves x 4 rows), then 3 global atomics into a replica slice.
    const int t = threadIdx.x;
    if (t < NCELL) {
        const int bb = t >> 4;
        const int c  = t & 15;
        const int qq = c >> 2, jj = c & 3;
        unsigned int cnt = 0, tsum = 0, psum = 0;
#pragma unroll
        for (int m = 0; m < 16; ++m) {  // m = w*4 + r
            unsigned int v = h[(m * 4 + qq) * 60 + jj * NBINS + bb];
            cnt  += v >> 25;
            tsum += (v >> 18) & 127u;
            psum += v & 0x3FFFFu;
        }
        float* rp = ws + (blockIdx.x & (nrep - 1)) * (3 * NCELL);
        atomicAdd(&rp[t],             (float)cnt);
        atomicAdd(&rp[NCELL + t],     (float)psum * (1.0f / 1024.0f));
        atomicAdd(&rp[2 * NCELL + t], (float)tsum);
    }
}

// Kernel 2: sum replicas, 240-cell epilogue -> scalar, double precision.
__global__ void __launch_bounds__(256) ece_final(const float* __restrict__ ws,
                                                 float* __restrict__ out, int nrep) {
    __shared__ double s_term[256];
    __shared__ int s_ne[256];
    int i = threadIdx.x;
    double term = 0.0;
    int ne = 0;
    if (i < NCELL) {
        float cnt = 0.0f, sp = 0.0f, st = 0.0f;
        for (int rep = 0; rep < nrep; ++rep) {
            const float* r = ws + rep * (3 * NCELL);
            cnt += r[i];
            sp  += r[NCELL + i];
            st  += r[2 * NCELL + i];
        }
        if (cnt > 0.0f) {
            ne = 1;
            term = fabs((double)sp / (double)cnt - (double)st / (double)cnt) *
                   ((double)cnt / BROWS);
        }
    }
    s_term[i] = term;
    s_ne[i] = ne;
    __syncthreads();
    for (int off = 128; off > 0; off >>= 1) {
        if (i < off) {
            s_term[i] += s_term[i + off];
            s_ne[i]   += s_ne[i + off];
        }
        __syncthreads();
    }
    if (i == 0) out[0] = (s_ne[0] > 0) ? (float)(s_term[0] / (double)s_ne[0]) : 0.0f;
}

extern "C" void kernel_launch(void* const* d_in, const int* in_sizes, int n_in,
                              void* d_out, int out_size, void* d_ws, size_t ws_size,
                              hipStream_t stream) {
    const float4* logits  = (const float4*)d_in[0];
    const float4* targets = (const float4*)d_in[1];
    float* ws  = (float*)d_ws;
    float* out = (float*)d_out;

    int nrep = MAXREP;
    while (nrep > 1 && (size_t)(nrep * 3 * NCELL * sizeof(float)) > ws_size) nrep >>= 1;

    (void)hipMemsetAsync(ws, 0, nrep * 3 * NCELL * sizeof(float), stream);
    ece_partial<<<GRID, 256, 0, stream>>>(logits, targets, ws, nrep);
    ece_final<<<1, 256, 0, stream>>>(ws, out, nrep);
}

// Round 10
// 270.310 us; speedup vs baseline: 1.0345x; 1.0345x over previous
//
#include <hip/hip_runtime.h>
#include <math.h>

#define NC 16
#define NBINS 15
#define NCELL (NC * NBINS)   // 240
#define GRID 2048
#define VITERS 16            // float4s per thread: 2048*256*16*4 = 33,554,432 elems
#define BROWS 2097152.0      // B (rows)
#define MAXREP 8

typedef float floatx4 __attribute__((ext_vector_type(4)));

// VALU-pipe cross-lane add within rows of 16 (row_shr, 0-fill at row edge).
template <int CTRL>
__device__ __forceinline__ unsigned int dpp_add(unsigned int v) {
    return v + (unsigned int)__builtin_amdgcn_update_dpp(0, (int)v, CTRL, 0xF, 0xF, true);
}

// Non-temporal 16B load (nt bit): logits don't allocate in L3, so targets
// (134 MB) stay L3-resident across dispatches. Proven +20% in R8.
__device__ __forceinline__ float4 ldnt(const float4* p) {
    floatx4 v = __builtin_nontemporal_load((const floatx4*)p);
    return make_float4(v.x, v.y, v.z, v.w);
}

// R9 post-mortem: explicit prefetch spilled (WRITE_SIZE 5.8->76MB; compiler
// pins at 64 VGPR and spills rather than grow) -> reverted. Root cause of the
// pressure AND of the 43us VALU busy-time is the 60-reg acc + 15-way
// cmp/cndmask scatter (~45 of 53 VALU ops/elem). This round composes the two
// PROVEN wins: nt-logits (R8) + LDS-atomic scatter (R0/R3: one no-return
// ds_add_u32/elem, VALU busy ~16us measured, DS pipe ~5us by throughput).
// Freeing the acc registers lets k+=4 keep 8 dwordx4 in flight (~64KB/CU)
// with no spill. h1: 64 rows (bin*4+j, rows 60-63 = p==1 dump) x 256 cols,
// col = threadIdx.x -> bank = col%32, 2 lanes/bank = free (m136). 64KB LDS
// -> 2 blocks/CU. Flush: read own column (conflict-free), R6's proven DPP
// shr4+shr8 fold, staging aliased into h1 after a barrier, 240 reducers,
// 3 global atomics into replica slices.
__global__ void __launch_bounds__(256, 2)
ece_partial(const float4* __restrict__ logits,
            const float4* __restrict__ targets,
            float* __restrict__ ws, int nrep) {
    __shared__ unsigned int h1[64 * 256];  // 64 KB

    const float LOG2E = 1.4426950408889634f;
    const int tid = blockIdx.x * 256 + threadIdx.x;
    const int S   = GRID * 256;  // float4 stride
    const int col = threadIdx.x;

#pragma unroll
    for (int r = 0; r < 64; ++r) h1[r * 256 + col] = 0u;
    __syncthreads();

    for (int k = 0; k < VITERS; k += 4) {
        float4 lv[4], tv[4];
#pragma unroll
        for (int m = 0; m < 4; ++m) {        // 8 dwordx4 issued before first use
            int i = tid + (k + m) * S;
            lv[m] = ldnt(&logits[i]);
            tv[m] = targets[i];
        }
#pragma unroll
        for (int m = 0; m < 4; ++m) {
            float xs[4]  = {lv[m].x, lv[m].y, lv[m].z, lv[m].w};
            float tvs[4] = {tv[m].x, tv[m].y, tv[m].z, tv[m].w};
#pragma unroll
            for (int j = 0; j < 4; ++j) {
                float e = __builtin_amdgcn_exp2f(-xs[j] * LOG2E);
                float p = __builtin_amdgcn_rcpf(1.0f + e);
                int b = ((int)(p * 15.0f)) & 15;  // p==1 -> row group 15 = dump
                // t*2^18 + p*1024 + 0.5 exact in fp32 -> (t<<18)|round(p*1024)
                unsigned int u = (unsigned int)(fmaf(tvs[j], 262144.0f,
                                                     fmaf(p, 1024.0f, 0.5f))) +
                                 (1u << 25);
                atomicAdd(&h1[(b * 4 + j) * 256 + col], u);  // ds_add_u32
            }
        }
    }
    __syncthreads();

    // Read own column (bank = col%32 for every row: conflict-free), skip dump
    // rows 60-63. Per cell <= 16 elems; packed cnt[31:25]|t[24:18]|p[17:0].
    unsigned int acc[4][NBINS];
#pragma unroll
    for (int b = 0; b < NBINS; ++b)
#pragma unroll
        for (int j = 0; j < 4; ++j) acc[j][b] = h1[(b * 4 + j) * 256 + col];
    __syncthreads();  // everyone done reading h1 -> safe to reuse as staging

    // Fold the 4 same-class lanes of each row (lanes l, l+4, l+8, l+12 share
    // col&3): after shr4+shr8, lane 12+q of each 16-row holds the group sum.
    // Post-fold <= 64 elems: cnt<=64<127, tsum<=64, psum<=65536<2^18 ok.
#pragma unroll
    for (int j = 0; j < 4; ++j)
#pragma unroll
        for (int b = 0; b < NBINS; ++b) {
            unsigned int v = acc[j][b];
            v = dpp_add<0x114>(v);  // row_shr:4
            v = dpp_add<0x118>(v);  // row_shr:8
            acc[j][b] = v;
        }

    const int lane = threadIdx.x & 63;
    const int w    = threadIdx.x >> 6;
    const int r    = lane >> 4;
    const int q    = lane & 3;
    if ((lane & 15) >= 12) {  // writer lanes 12+q of each row, q = lane&3
        unsigned int* dst = &h1[((w * 4 + r) * 4 + q) * 60];
#pragma unroll
        for (int j = 0; j < 4; ++j)
#pragma unroll
            for (int b = 0; b < NBINS; ++b) dst[j * NBINS + b] = acc[j][b];
    }
    __syncthreads();

    // 240 reducers: cell (bin bb, class c = 4*qq + jj) = sum of 16 partials
    // (4 waves x 4 rows), then 3 global atomics into a replica slice.
    const int t = threadIdx.x;
    if (t < NCELL) {
        const int bb = t >> 4;
        const int c  = t & 15;
        const int qq = c >> 2, jj = c & 3;
        unsigned int cnt = 0, tsum = 0, psum = 0;
#pragma unroll
        for (int m = 0; m < 16; ++m) {  // m = w*4 + r
            unsigned int v = h1[(m * 4 + qq) * 60 + jj * NBINS + bb];
            cnt  += v >> 25;
            tsum += (v >> 18) & 127u;
            psum += v & 0x3FFFFu;
        }
        float* rp = ws + (blockIdx.x & (nrep - 1)) * (3 * NCELL);
        atomicAdd(&rp[t],             (float)cnt);
        atomicAdd(&rp[NCELL + t],     (float)psum * (1.0f / 1024.0f));
        atomicAdd(&rp[2 * NCELL + t], (float)tsum);
    }
}

// Kernel 2: sum replicas, 240-cell epilogue -> scalar, double precision.
__global__ void __launch_bounds__(256) ece_final(const float* __restrict__ ws,
                                                 float* __restrict__ out, int nrep) {
    __shared__ double s_term[256];
    __shared__ int s_ne[256];
    int i = threadIdx.x;
    double term = 0.0;
    int ne = 0;
    if (i < NCELL) {
        float cnt = 0.0f, sp = 0.0f, st = 0.0f;
        for (int rep = 0; rep < nrep; ++rep) {
            const float* r = ws + rep * (3 * NCELL);
            cnt += r[i];
            sp  += r[NCELL + i];
            st  += r[2 * NCELL + i];
        }
        if (cnt > 0.0f) {
            ne = 1;
            term = fabs((double)sp / (double)cnt - (double)st / (double)cnt) *
                   ((double)cnt / BROWS);
        }
    }
    s_term[i] = term;
    s_ne[i] = ne;
    __syncthreads();
    for (int off = 128; off > 0; off >>= 1) {
        if (i < off) {
            s_term[i] += s_term[i + off];
            s_ne[i]   += s_ne[i + off];
        }
        __syncthreads();
    }
    if (i == 0) out[0] = (s_ne[0] > 0) ? (float)(s_term[0] / (double)s_ne[0]) : 0.0f;
}

extern "C" void kernel_launch(void* const* d_in, const int* in_sizes, int n_in,
                              void* d_out, int out_size, void* d_ws, size_t ws_size,
                              hipStream_t stream) {
    const float4* logits  = (const float4*)d_in[0];
    const float4* targets = (const float4*)d_in[1];
    float* ws  = (float*)d_ws;
    float* out = (float*)d_out;

    int nrep = MAXREP;
    while (nrep > 1 && (size_t)(nrep * 3 * NCELL * sizeof(float)) > ws_size) nrep >>= 1;

    (void)hipMemsetAsync(ws, 0, nrep * 3 * NCELL * sizeof(float), stream);
    ece_partial<<<GRID, 256, 0, stream>>>(logits, targets, ws, nrep);
    ece_final<<<1, 256, 0, stream>>>(ws, out, nrep);
}

// Round 11
// 268.001 us; speedup vs baseline: 1.0434x; 1.0086x over previous
//
#include <hip/hip_runtime.h>
#include <math.h>

#define NC 16
#define NBINS 15
#define NCELL (NC * NBINS)   // 240
#define GRID 2048
#define VITERS 16            // float4s per thread: 2048*256*16*4 = 33,554,432 elems
#define BROWS 2097152.0      // B (rows)
#define MAXREP 8

typedef float floatx4 __attribute__((ext_vector_type(4)));

// VALU-pipe cross-lane add within rows of 16 (row_shr, 0-fill at row edge).
template <int CTRL>
__device__ __forceinline__ unsigned int dpp_add(unsigned int v) {
    return v + (unsigned int)__builtin_amdgcn_update_dpp(0, (int)v, CTRL, 0xF, 0xF, true);
}

// Non-temporal 16B load (nt bit): logits don't allocate in L3, so targets
// (134 MB) stay L3-resident across dispatches. Proven +20% in R8.
__device__ __forceinline__ float4 ldnt(const float4* p) {
    floatx4 v = __builtin_nontemporal_load((const floatx4*)p);
    return make_float4(v.x, v.y, v.z, v.w);
}

// R10 post-mortem: LDS-scatter + nt = 79us (best), VALU busy down to 15us as
// predicted, no spill — but logits stream only 1.7 TB/s while a fillBuffer in
// the same trace does 6.9 TB/s. Occupancy 19% (64KB LDS -> 2 blocks/CU) is
// the starved resource: ~1.5 waves/SIMD can't cover the 4 exposed vmcnt waits
// per block. THIS ROUND: histogram 64KB -> 16KB by sharing each column among
// the 4 waves (col = tid&63; within-wave lanes still distinct -> conflict-
// free; cross-wave same-address handled by ds_add). ~5 blocks/CU, ~20
// waves/CU. Capacity/cell <= 64 elems: cnt[31:25]<=64<127, t[24:18]<=64,
// p_fix[17:0]<=65536<2^18 -> no carry. Flush gets cheaper: columns already
// merge waves, so wave w reduces slot j=w (15 regs), DPP shr4+shr8 fold,
// stage 4 row-partials/cell, reducer sums 4.
__global__ void __launch_bounds__(256, 4)
ece_partial(const float4* __restrict__ logits,
            const float4* __restrict__ targets,
            float* __restrict__ ws, int nrep) {
    __shared__ unsigned int h1[64 * 64];     // 16 KB histogram
    __shared__ unsigned int stg[16 * 60];    // 3.75 KB staging (r*4+Q) x (j*15+b)

    const float LOG2E = 1.4426950408889634f;
    const int tid = blockIdx.x * 256 + threadIdx.x;
    const int S   = GRID * 256;  // float4 stride
    const int col = threadIdx.x & 63;

#pragma unroll
    for (int r = 0; r < 16; ++r) h1[r * 256 + threadIdx.x] = 0u;
    if (threadIdx.x < 240) {
#pragma unroll
        for (int m = 0; m < 4; ++m) stg[m * 240 + threadIdx.x] = 0u;
    }
    __syncthreads();

    for (int k = 0; k < VITERS; k += 4) {
        float4 lv[4], tv[4];
#pragma unroll
        for (int m = 0; m < 4; ++m) {        // 8 dwordx4 issued before first use
            int i = tid + (k + m) * S;
            lv[m] = ldnt(&logits[i]);
            tv[m] = targets[i];
        }
#pragma unroll
        for (int m = 0; m < 4; ++m) {
            float xs[4]  = {lv[m].x, lv[m].y, lv[m].z, lv[m].w};
            float tvs[4] = {tv[m].x, tv[m].y, tv[m].z, tv[m].w};
#pragma unroll
            for (int j = 0; j < 4; ++j) {
                float e = __builtin_amdgcn_exp2f(-xs[j] * LOG2E);
                float p = __builtin_amdgcn_rcpf(1.0f + e);
                int b = ((int)(p * 15.0f)) & 15;  // p==1 -> rows 60-63 = dump
                // t*2^18 + p*1024 + 0.5 exact in fp32 -> (t<<18)|round(p*1024)
                unsigned int u = (unsigned int)(fmaf(tvs[j], 262144.0f,
                                                     fmaf(p, 1024.0f, 0.5f))) +
                                 (1u << 25);
                atomicAdd(&h1[(b * 4 + j) * 64 + col], u);  // ds_add_u32
            }
        }
    }
    __syncthreads();

    // Flush. Columns already hold the 4-wave merged partials, so wave w
    // reduces slot j = w only: lane l reads column l's 15 bin values
    // (conflict-free), folds the 4 same-Q lanes of each 16-row (shr4+shr8),
    // writer lanes 12+Q of row r stage partial (r, Q).
    const int lane = threadIdx.x & 63;
    const int w    = threadIdx.x >> 6;   // = j slice this wave reduces
    {
        unsigned int v[NBINS];
#pragma unroll
        for (int b = 0; b < NBINS; ++b) v[b] = h1[(b * 4 + w) * 64 + lane];
#pragma unroll
        for (int b = 0; b < NBINS; ++b) {
            unsigned int x = v[b];
            x = dpp_add<0x114>(x);  // row_shr:4
            x = dpp_add<0x118>(x);  // row_shr:8
            v[b] = x;               // lane 16r+12+Q: sum over {Q,4+Q,8+Q,12+Q}
        }
        if ((lane & 15) >= 12) {
            const int r = lane >> 4, q = lane & 3;
            unsigned int* dst = &stg[(r * 4 + q) * 60 + w * 15];
#pragma unroll
            for (int b = 0; b < NBINS; ++b) dst[b] = v[b];
        }
    }
    __syncthreads();

    // 240 reducers: cell (bin bb, class 4Q+jj) = sum of 4 row-partials,
    // then 3 global atomics into a replica slice.
    const int t = threadIdx.x;
    if (t < NCELL) {
        const int bb = t >> 4;
        const int c  = t & 15;
        const int Q  = c >> 2, jj = c & 3;
        unsigned int cnt = 0, tsum = 0, psum = 0;
#pragma unroll
        for (int r = 0; r < 4; ++r) {
            unsigned int v = stg[(r * 4 + Q) * 60 + jj * 15 + bb];
            cnt  += v >> 25;
            tsum += (v >> 18) & 127u;
            psum += v & 0x3FFFFu;
        }
        float* rp = ws + (blockIdx.x & (nrep - 1)) * (3 * NCELL);
        atomicAdd(&rp[t],             (float)cnt);
        atomicAdd(&rp[NCELL + t],     (float)psum * (1.0f / 1024.0f));
        atomicAdd(&rp[2 * NCELL + t], (float)tsum);
    }
}

// Kernel 2: sum replicas, 240-cell epilogue -> scalar, double precision.
__global__ void __launch_bounds__(256) ece_final(const float* __restrict__ ws,
                                                 float* __restrict__ out, int nrep) {
    __shared__ double s_term[256];
    __shared__ int s_ne[256];
    int i = threadIdx.x;
    double term = 0.0;
    int ne = 0;
    if (i < NCELL) {
        float cnt = 0.0f, sp = 0.0f, st = 0.0f;
        for (int rep = 0; rep < nrep; ++rep) {
            const float* r = ws + rep * (3 * NCELL);
            cnt += r[i];
            sp  += r[NCELL + i];
            st  += r[2 * NCELL + i];
        }
        if (cnt > 0.0f) {
            ne = 1;
            term = fabs((double)sp / (double)cnt - (double)st / (double)cnt) *
                   ((double)cnt / BROWS);
        }
    }
    s_term[i] = term;
    s_ne[i] = ne;
    __syncthreads();
    for (int off = 128; off > 0; off >>= 1) {
        if (i < off) {
            s_term[i] += s_term[i + off];
            s_ne[i]   += s_ne[i + off];
        }
        __syncthreads();
    }
    if (i == 0) out[0] = (s_ne[0] > 0) ? (float)(s_term[0] / (double)s_ne[0]) : 0.0f;
}

extern "C" void kernel_launch(void* const* d_in, const int* in_sizes, int n_in,
                              void* d_out, int out_size, void* d_ws, size_t ws_size,
                              hipStream_t stream) {
    const float4* logits  = (const float4*)d_in[0];
    const float4* targets = (const float4*)d_in[1];
    float* ws  = (float*)d_ws;
    float* out = (float*)d_out;

    int nrep = MAXREP;
    while (nrep > 1 && (size_t)(nrep * 3 * NCELL * sizeof(float)) > ws_size) nrep >>= 1;

    (void)hipMemsetAsync(ws, 0, nrep * 3 * NCELL * sizeof(float), stream);
    ece_partial<<<GRID, 256, 0, stream>>>(logits, targets, ws, nrep);
    ece_final<<<1, 256, 0, stream>>>(ws, out, nrep);
}